// Round 9
// baseline (80.654 us; speedup 1.0000x reference)
//
#include <hip/hip_runtime.h>
#include <hip/hip_bf16.h>
#include <cstddef>
#include <cstdint>

// LinearAttention fused pipeline, MI355X gfx950.
// x:[16,64,64,128] f32, w_qkv:[128,384], w_out:[128,128], b_out/g_ln/b_ln:[128]
// Pipeline (5 kernels):
//   K1 k_transpose_wqkv: w_qkv -> w_qkv^T bf16
//   K2 k_q_exp: eq = exp(x @ W_q) UNNORMALIZED -> bf16 (out_ln-skeleton:
//      no LDS, no barriers, no shuffles, no divides). Softmax normalization
//      is deferred to K5 (linear w.r.t. GEMM2, per-head scale).
//   K3 k_kv_ctx: (R3-proven, f32 x) k,v GEMMs + exp(k) -> LDS transpose ->
//      per-head ctx[32][32] partial MFMA + ksum via MFMA(ones).
//   K4 k_weff64: reduce ctx partials, ctxn=ctx/ksum, W_eff^T bf16 (k-dim
//      stored permuted d'=2*(d&15)+(d>>4), matching eq's packed layout).
//   K5 k_out_ln: sumh from A-frags (8 adds + 2 shfl per (mf,h)) ->
//      out = LN( Σ_h (SCALE/sumh)·(eq_h @ W_eff_h) + b_out ).
// Evidence R3-R8: q-path epilogue (softmax shfl-chains+divides) was a ~40us
// invariant; kv_ctx=10us & out_ln=9us prove GEMM+stores+exp are cheap.

typedef __attribute__((ext_vector_type(8))) short short8_t;
typedef __attribute__((ext_vector_type(4))) float f32x4;

#define SCALE_Q 0.17677669529663687f
#define EPS_LN 1e-5f

__device__ __forceinline__ unsigned short f2bf(float f) {
  union { float f; unsigned u; } v; v.f = f;
  unsigned r = (v.u + 0x7FFFu + ((v.u >> 16) & 1u)) >> 16;
  return (unsigned short)r;
}
__device__ __forceinline__ float bf2f(unsigned short u) {
  union { float f; unsigned u; } v; v.u = ((unsigned)u) << 16;
  return v.f;
}
// pack 2 f32 -> 2 bf16 (truncate): low16 = f0, high16 = f1
__device__ __forceinline__ unsigned pack2(float f0, float f1) {
  union { float f; unsigned u; } a, b; a.f = f0; b.f = f1;
  return __builtin_amdgcn_perm(b.u, a.u, 0x07060302);
}
// pack 8 f32 -> 8 bf16 by truncation: 4x v_perm_b32
__device__ __forceinline__ short8_t trunc8(float4 lo, float4 hi) {
  union { float4 f; unsigned u[4]; } a, b;
  union { unsigned u[4]; short8_t s; } r;
  a.f = lo; b.f = hi;
  r.u[0] = __builtin_amdgcn_perm(a.u[1], a.u[0], 0x07060302);
  r.u[1] = __builtin_amdgcn_perm(a.u[3], a.u[2], 0x07060302);
  r.u[2] = __builtin_amdgcn_perm(b.u[1], b.u[0], 0x07060302);
  r.u[3] = __builtin_amdgcn_perm(b.u[3], b.u[2], 0x07060302);
  return r.s;
}

// ---------------- K1: transpose + bf16 convert w_qkv [128][384] -> [384][128]
__global__ void k_transpose_wqkv(const float* __restrict__ w,
                                 unsigned short* __restrict__ wT) {
  int c = blockIdx.x * 4 + (threadIdx.x >> 6);   // 96 blocks -> c < 384
  int l = threadIdx.x & 63;
  float f0 = w[(size_t)(2 * l) * 384 + c];
  float f1 = w[(size_t)(2 * l + 1) * 384 + c];
  ((unsigned*)(wT + (size_t)c * 128))[l] = pack2(f0, f1);
}

// ---------------- K2: eq = exp(x @ W_q), unnormalized, packed-permuted bf16
// grid 512 (128 tokens/block), 4 waves, wave = 32 rows x 128 cols.
// No LDS, no barriers. Store layout within head p: d' = 2*lr + (nf&1).
__global__ __launch_bounds__(256, 2)
void k_q_exp(const float* __restrict__ x, const unsigned short* __restrict__ wT,
             unsigned short* __restrict__ eq) {
  int tid = threadIdx.x;
  int rowBase = blockIdx.x * 128;
  int lane = tid & 63;
  int w = tid >> 6;
  int lr = lane & 15;
  int kg = lane >> 4;

  // A fragments from x (f32 -> bf16 truncate), rows w*32 + mf*16 + lr
  short8_t a[2][4];  // [mf][kk]
  {
    const float* ap = x + (size_t)(rowBase + w * 32 + lr) * 128 + kg * 8;
#pragma unroll
    for (int mf = 0; mf < 2; ++mf) {
      const float* r = ap + (size_t)mf * 16 * 128;
#pragma unroll
      for (int kk = 0; kk < 4; ++kk)
        a[mf][kk] = trunc8(*(const float4*)(r + kk * 32),
                           *(const float4*)(r + kk * 32 + 4));
    }
  }

  f32x4 acc[2][8] = {};
#pragma unroll
  for (int kk = 0; kk < 4; ++kk) {
    short8_t bf[8];
#pragma unroll
    for (int nf = 0; nf < 8; ++nf)
      bf[nf] = *(const short8_t*)(wT + (size_t)(nf * 16 + lr) * 128 + kk * 32 + kg * 8);
#pragma unroll
    for (int mf = 0; mf < 2; ++mf)
#pragma unroll
      for (int nf = 0; nf < 8; ++nf)
        acc[mf][nf] = __builtin_amdgcn_mfma_f32_16x16x32_bf16(a[mf][kk], bf[nf], acc[mf][nf], 0, 0, 0);
  }

  // epilogue: exp + pack pairs (nf even/odd) + coalesced dword stores
#pragma unroll
  for (int mf = 0; mf < 2; ++mf)
#pragma unroll
    for (int p = 0; p < 4; ++p)
#pragma unroll
      for (int j = 0; j < 4; ++j) {
        float e0 = __expf(acc[mf][2 * p][j]);
        float e1 = __expf(acc[mf][2 * p + 1][j]);
        size_t ro = (size_t)(rowBase + w * 32 + mf * 16 + kg * 4 + j) * 128;
        *(unsigned*)&eq[ro + p * 32 + 2 * lr] = pack2(e0, e1);
      }
}

// ---------------- K3: k+v GEMMs (f32 x) + in-tile ctx partial + MFMA ksum
// grid 512 (one per 128-token tile). ctxp[blk][h][32][32] f32, ksump[blk][128].
__global__ __launch_bounds__(256, 2)
void k_kv_ctx(const float* __restrict__ x, const unsigned short* __restrict__ wT,
              float* __restrict__ ctxp, float* __restrict__ ksump) {
  __shared__ short Bk[128][136];  // k weights; later reused as ekT[d][token]
  __shared__ short Bv[128][136];  // v weights; later reused as vT[e][token]

  int tid = threadIdx.x;
  int rb = blockIdx.x;
  int rowBase = rb * 128;

  { // stage Bk, Bv from wT parts 1 and 2 (coalesced)
    const unsigned short* wk = wT + (size_t)1 * 128 * 128;
    const unsigned short* wv2 = wT + (size_t)2 * 128 * 128;
#pragma unroll
    for (int i = 0; i < 8; ++i) {
      int idx = i * 256 + tid;
      int n = idx >> 4;
      int k8 = (idx & 15) << 3;
      *(short8_t*)&Bk[n][k8] = *(const short8_t*)(wk + (size_t)n * 128 + k8);
      *(short8_t*)&Bv[n][k8] = *(const short8_t*)(wv2 + (size_t)n * 128 + k8);
    }
  }

  int lane = tid & 63;
  int wv = tid >> 6;
  int wr = wv >> 1, wc = wv & 1;
  int lr = lane & 15;
  int kg = lane >> 4;

  // A fragments: load x f32 and convert once; reused by both GEMMs
  short8_t abf[4][4];  // [kk][mf]
  {
    const float* ap = x + (size_t)(rowBase + wr * 64 + lr) * 128 + kg * 8;
#pragma unroll
    for (int mf = 0; mf < 4; ++mf) {
      const float* r = ap + (size_t)mf * 16 * 128;
#pragma unroll
      for (int kk = 0; kk < 4; ++kk)
        abf[kk][mf] = trunc8(*(const float4*)(r + kk * 32),
                             *(const float4*)(r + kk * 32 + 4));
    }
  }
  __syncthreads();  // Bk/Bv staged

  // k GEMM -> exp -> packed bf16 (4 tokens per uint2)
  uint2 ekp[4][4], vp[4][4];
  {
    f32x4 acc[4][4] = {};
#pragma unroll
    for (int kk = 0; kk < 4; ++kk) {
      short8_t bf[4];
#pragma unroll
      for (int nf = 0; nf < 4; ++nf)
        bf[nf] = *(const short8_t*)&Bk[wc * 64 + nf * 16 + lr][kk * 32 + kg * 8];
#pragma unroll
      for (int mf = 0; mf < 4; ++mf)
#pragma unroll
        for (int nf = 0; nf < 4; ++nf)
          acc[mf][nf] = __builtin_amdgcn_mfma_f32_16x16x32_bf16(abf[kk][mf], bf[nf], acc[mf][nf], 0, 0, 0);
    }
#pragma unroll
    for (int mf = 0; mf < 4; ++mf)
#pragma unroll
      for (int nf = 0; nf < 4; ++nf) {
        ekp[mf][nf].x = pack2(__expf(acc[mf][nf][0]), __expf(acc[mf][nf][1]));
        ekp[mf][nf].y = pack2(__expf(acc[mf][nf][2]), __expf(acc[mf][nf][3]));
      }
  }
  // v GEMM -> packed bf16
  {
    f32x4 acc[4][4] = {};
#pragma unroll
    for (int kk = 0; kk < 4; ++kk) {
      short8_t bf[4];
#pragma unroll
      for (int nf = 0; nf < 4; ++nf)
        bf[nf] = *(const short8_t*)&Bv[wc * 64 + nf * 16 + lr][kk * 32 + kg * 8];
#pragma unroll
      for (int mf = 0; mf < 4; ++mf)
#pragma unroll
        for (int nf = 0; nf < 4; ++nf)
          acc[mf][nf] = __builtin_amdgcn_mfma_f32_16x16x32_bf16(abf[kk][mf], bf[nf], acc[mf][nf], 0, 0, 0);
    }
#pragma unroll
    for (int mf = 0; mf < 4; ++mf)
#pragma unroll
      for (int nf = 0; nf < 4; ++nf) {
        vp[mf][nf].x = pack2(acc[mf][nf][0], acc[mf][nf][1]);
        vp[mf][nf].y = pack2(acc[mf][nf][2], acc[mf][nf][3]);
      }
  }
  __syncthreads();  // all waves done reading Bk/Bv

  // transposed LDS write: ekT[channel][token], vT[channel][token]
  short (*ekT)[136] = Bk;
  short (*vT)[136] = Bv;
#pragma unroll
  for (int mf = 0; mf < 4; ++mf) {
    int t0 = wr * 64 + mf * 16 + kg * 4;  // 4 consecutive tokens
#pragma unroll
    for (int nf = 0; nf < 4; ++nf) {
      int col = wc * 64 + nf * 16 + lr;
      *(uint2*)&ekT[col][t0] = ekp[mf][nf];
      *(uint2*)&vT[col][t0] = vp[mf][nf];
    }
  }
  __syncthreads();

  // per-head ctx MFMA (wave = head) + ksum via MFMA with ones-vector
  {
    int h = wv;
    union { unsigned u[4]; short8_t s; } ones;
#pragma unroll
    for (int i = 0; i < 4; ++i) ones.u[i] = 0x3F803F80u;  // bf16 1.0 x2

    f32x4 c2[2][2] = {};
    f32x4 ks2[2] = {};
#pragma unroll
    for (int kk = 0; kk < 4; ++kk) {
      short8_t a2[2], b2[2];
#pragma unroll
      for (int m2 = 0; m2 < 2; ++m2)
        a2[m2] = *(const short8_t*)&ekT[h * 32 + m2 * 16 + lr][kk * 32 + kg * 8];
#pragma unroll
      for (int n2 = 0; n2 < 2; ++n2)
        b2[n2] = *(const short8_t*)&vT[h * 32 + n2 * 16 + lr][kk * 32 + kg * 8];
#pragma unroll
      for (int m2 = 0; m2 < 2; ++m2) {
#pragma unroll
        for (int n2 = 0; n2 < 2; ++n2)
          c2[m2][n2] = __builtin_amdgcn_mfma_f32_16x16x32_bf16(a2[m2], b2[n2], c2[m2][n2], 0, 0, 0);
        ks2[m2] = __builtin_amdgcn_mfma_f32_16x16x32_bf16(a2[m2], ones.s, ks2[m2], 0, 0, 0);
      }
    }
    float* cp = ctxp + ((size_t)rb * 4 + h) * 1024;
#pragma unroll
    for (int m2 = 0; m2 < 2; ++m2)
#pragma unroll
      for (int n2 = 0; n2 < 2; ++n2)
#pragma unroll
        for (int j = 0; j < 4; ++j)
          cp[(m2 * 16 + kg * 4 + j) * 32 + n2 * 16 + lr] = c2[m2][n2][j];
    if (lr == 0) {  // every col of ks2 identical
#pragma unroll
      for (int m2 = 0; m2 < 2; ++m2)
#pragma unroll
        for (int j = 0; j < 4; ++j)
          ksump[(size_t)rb * 128 + h * 32 + m2 * 16 + kg * 4 + j] = ks2[m2][j];
    }
  }
}

// ---------------- K4: per (b,h) reduce partials + build W_eff^T cols
// grid 64. Stores k-dim PERMUTED to match eq: new index = h*32 + 2*dd + dg.
__global__ __launch_bounds__(256, 4)
void k_weff64(const float* __restrict__ ctxp, const float* __restrict__ ksump,
              const float* __restrict__ wout, unsigned short* __restrict__ weffT) {
  __shared__ float wo[32][128];  // wout rows h*32+e
  __shared__ float cn[32][32];   // ctxn[d][e]
  __shared__ float ksh[32];
  int tid = threadIdx.x;
  int b = blockIdx.x >> 2, h = blockIdx.x & 3;

#pragma unroll
  for (int i = 0; i < 16; ++i) {
    int idx = i * 256 + tid;
    int e = idx >> 7, jj = idx & 127;
    wo[e][jj] = wout[(h * 32 + e) * 128 + jj];
  }
  if (tid < 32) {
    float s = 0;
    for (int c = 0; c < 32; ++c)
      s += ksump[(size_t)(b * 32 + c) * 128 + h * 32 + tid];
    ksh[tid] = s;
  }
  __syncthreads();
#pragma unroll
  for (int i = 0; i < 4; ++i) {
    int idx = i * 256 + tid;
    int d = idx >> 5;
    float s = 0;
    for (int c = 0; c < 32; ++c)
      s += ctxp[((size_t)(b * 32 + c) * 4 + h) * 1024 + idx];
    cn[d][idx & 31] = s / ksh[d];
  }
  __syncthreads();

  // thread (j, half8): 16 dots -> 8 packed dwords (d'=2*dd+dg), 2x uint4 store
  int j = tid >> 1, h8 = (tid & 1) * 8;
  unsigned pk[8];
#pragma unroll
  for (int t = 0; t < 8; ++t) {
    int dd = h8 + t;
    float s0 = 0, s1 = 0;
#pragma unroll
    for (int e = 0; e < 32; ++e) {
      float w = wo[e][j];
      s0 += cn[dd][e] * w;
      s1 += cn[16 + dd][e] * w;
    }
    pk[t] = pack2(s0, s1);  // low=d'=2dd, high=d'=2dd+1
  }
  unsigned* outp = (unsigned*)(weffT + (size_t)b * 16384 + j * 128 + h * 32 + 2 * h8);
  *(uint4*)outp = make_uint4(pk[0], pk[1], pk[2], pk[3]);
  *(uint4*)(outp + 4) = make_uint4(pk[4], pk[5], pk[6], pk[7]);
}

// ---------------- K5: out = LN( Σ_h (SCALE/sumh)·(eq_h @ W_eff_h) + b_out )
// grid 512; wave w owns rows w*32..+31, all 128 cols. No LDS, no barriers.
__global__ __launch_bounds__(256, 2)
void k_out_ln(const unsigned short* __restrict__ eq, const unsigned short* __restrict__ weffT,
              const float* __restrict__ b_out, const float* __restrict__ g_ln,
              const float* __restrict__ b_ln, float* __restrict__ out) {
  int tid = threadIdx.x;
  int rowBase = blockIdx.x * 128;
  int b = rowBase >> 12;
  int lane = tid & 63;
  int w = tid >> 6;
  int lr = lane & 15;
  int kg = lane >> 4;

  const unsigned short* bb = weffT + (size_t)b * 16384;

  // A fragments from eq (bf16, permuted-within-head layout)
  short8_t a[2][4];  // [mf][h]
  {
    const unsigned short* ap = eq + (size_t)(rowBase + w * 32 + lr) * 128 + kg * 8;
#pragma unroll
    for (int mf = 0; mf < 2; ++mf)
#pragma unroll
      for (int h = 0; h < 4; ++h)
        a[mf][h] = *(const short8_t*)(ap + (size_t)mf * 16 * 128 + h * 32);
  }

  // per-(mf,h): sumh for token (w*32+mf*16+lr); then rs broadcast to C-rows
  float rs[2][4][4];  // [mf][h][j] scale for C-row kg*4+j
#pragma unroll
  for (int mf = 0; mf < 2; ++mf)
#pragma unroll
    for (int h = 0; h < 4; ++h) {
      float s = 0;
#pragma unroll
      for (int i = 0; i < 8; ++i) s += bf2f((unsigned short)a[mf][h][i]);
      s += __shfl_xor(s, 16, 64);
      s += __shfl_xor(s, 32, 64);   // now s = sumh for token row lr (all kg)
      float r = SCALE_Q / s;
#pragma unroll
      for (int j = 0; j < 4; ++j)
        rs[mf][h][j] = __shfl(r, kg * 4 + j, 64);  // from lane lr=kg*4+j
    }

  // per-head K=32 MFMA + scaled accumulation
  f32x4 acc[2][8] = {};
  const f32x4 zero4 = {0.f, 0.f, 0.f, 0.f};
#pragma unroll
  for (int h = 0; h < 4; ++h) {
    short8_t bf[8];
#pragma unroll
    for (int nf = 0; nf < 8; ++nf)
      bf[nf] = *(const short8_t*)(bb + (size_t)(nf * 16 + lr) * 128 + h * 32 + kg * 8);
#pragma unroll
    for (int mf = 0; mf < 2; ++mf)
#pragma unroll
      for (int nf = 0; nf < 8; ++nf) {
        f32x4 t = __builtin_amdgcn_mfma_f32_16x16x32_bf16(a[mf][h], bf[nf], zero4, 0, 0, 0);
#pragma unroll
        for (int j = 0; j < 4; ++j)
          acc[mf][nf][j] += t[j] * rs[mf][h][j];
      }
  }

  // bias + LayerNorm + store
  float bo[8], gl[8], bl[8];
#pragma unroll
  for (int nf = 0; nf < 8; ++nf) {
    int c = nf * 16 + lr;
    bo[nf] = b_out[c]; gl[nf] = g_ln[c]; bl[nf] = b_ln[c];
  }
#pragma unroll
  for (int mf = 0; mf < 2; ++mf)
#pragma unroll
    for (int nf = 0; nf < 8; ++nf)
#pragma unroll
      for (int j = 0; j < 4; ++j) acc[mf][nf][j] += bo[nf];

#pragma unroll
  for (int mf = 0; mf < 2; ++mf) {
    float s[4] = {0, 0, 0, 0}, q[4] = {0, 0, 0, 0};
#pragma unroll
    for (int nf = 0; nf < 8; ++nf)
#pragma unroll
      for (int j = 0; j < 4; ++j) {
        float v = acc[mf][nf][j];
        s[j] += v; q[j] += v * v;
      }
#pragma unroll
    for (int j = 0; j < 4; ++j) {
#pragma unroll
      for (int d = 1; d < 16; d <<= 1) {
        s[j] += __shfl_xor(s[j], d, 64);
        q[j] += __shfl_xor(q[j], d, 64);
      }
    }
#pragma unroll
    for (int j = 0; j < 4; ++j) {
      float mean = s[j] * (1.0f / 128.0f);
      float var = q[j] * (1.0f / 128.0f) - mean * mean;
      float rstd = rsqrtf(var + EPS_LN);
      size_t ro = (size_t)(rowBase + w * 32 + mf * 16 + kg * 4 + j) * 128;
#pragma unroll
      for (int nf = 0; nf < 8; ++nf)
        out[ro + nf * 16 + lr] = (acc[mf][nf][j] - mean) * rstd * gl[nf] + bl[nf];
    }
  }
}

extern "C" void kernel_launch(void* const* d_in, const int* in_sizes, int n_in,
                              void* d_out, int out_size, void* d_ws, size_t ws_size,
                              hipStream_t stream) {
  const float* x     = (const float*)d_in[0];
  const float* w_qkv = (const float*)d_in[1];
  const float* w_out = (const float*)d_in[2];
  const float* b_out = (const float*)d_in[3];
  const float* g_ln  = (const float*)d_in[4];
  const float* b_ln  = (const float*)d_in[5];
  float* out = (float*)d_out;

  char* ws = (char*)d_ws;
  unsigned short* wqkvT = (unsigned short*)(ws + 0);          // 96 KB (128KB slot)
  float* ctxp           = (float*)(ws + 131072);              // 8 MB [512][4][32][32]
  float* ksump          = (float*)(ws + 131072 + 8388608);    // 256 KB [512][128]
  unsigned short* weffT = (unsigned short*)(ws + 131072 + 8388608 + 262144); // 512 KB
  unsigned short* eq    = (unsigned short*)(ws + 131072 + 8388608 + 262144 + 524288); // 16.78 MB

  k_transpose_wqkv<<<96, 256, 0, stream>>>(w_qkv, wqkvT);
  k_q_exp<<<512, 256, 0, stream>>>(x, wqkvT, eq);
  k_kv_ctx<<<512, 256, 0, stream>>>(x, wqkvT, ctxp, ksump);
  k_weff64<<<64, 256, 0, stream>>>(ctxp, ksump, w_out, weffT);
  k_out_ln<<<512, 256, 0, stream>>>(eq, weffT, b_out, g_ln, b_ln, out);
}